// Round 9
// baseline (324.893 us; speedup 1.0000x reference)
//
#include <hip/hip_runtime.h>
#include <stdint.h>

typedef __bf16 bf16x8 __attribute__((ext_vector_type(8)));
typedef float f32x4 __attribute__((ext_vector_type(4)));

#define CHB 8192  // edges per partition block
#define LDSROW 17 // uint4 per LDS row (272B, +16B pad to spread banks)

__device__ __forceinline__ unsigned short f2bf(float f) {
    union { float f; unsigned u; } x; x.f = f;
    unsigned r = x.u + 0x7fffu + ((x.u >> 16) & 1u);
    return (unsigned short)(r >> 16);
}

// acc += pk.bf16[0]*sel.bf16[0] + pk.bf16[1]*sel.bf16[1]  (one VOP3P op)
__device__ __forceinline__ void dot2acc(float& a, unsigned pk, unsigned sel) {
    asm("v_dot2_f32_bf16 %0, %1, %2, %0" : "+v"(a) : "v"(pk), "v"(sel));
}

// selector constants: bf16 pair (1.0, 0.0) and (0.0, 1.0)
#define SEL_LO 0x00003F80u
#define SEL_HI 0x3F800000u

#define DOT8(v)                                      \
    dot2acc(acc[0], (v).x, sel_lo); dot2acc(acc[1], (v).x, sel_hi); \
    dot2acc(acc[2], (v).y, sel_lo); dot2acc(acc[3], (v).y, sel_hi); \
    dot2acc(acc[4], (v).z, sel_lo); dot2acc(acc[5], (v).z, sel_hi); \
    dot2acc(acc[6], (v).w, sel_lo); dot2acc(acc[7], (v).w, sel_hi);

#define DOT4(v)                                      \
    dot2acc(acc[0], (v).x, sel_lo); dot2acc(acc[1], (v).x, sel_hi); \
    dot2acc(acc[2], (v).y, sel_lo); dot2acc(acc[3], (v).y, sel_hi);

// ---------- pass A: per-(bucket,block) histogram. bucket = dst>>9 ----------
__global__ __launch_bounds__(256) void k_hist(const int* __restrict__ dst, int E, int nPB,
                                              int* __restrict__ bhist, int NB) {
    __shared__ int h[256];
    int t = threadIdx.x;
    h[t] = 0;
    __syncthreads();
    int blk = blockIdx.x;
    int hi = min((blk + 1) * CHB, E);
    for (int e = blk * CHB + t; e < hi; e += 256) atomicAdd(&h[dst[e] >> 9], 1);
    __syncthreads();
    if (t < NB) bhist[t * nPB + blk] = h[t];
}

// ---------- hierarchical scan (generic): in[M] -> out[M+1] exclusive ----------
__global__ __launch_bounds__(256) void k_scan_part(const int* __restrict__ deg,
                                                   int* __restrict__ part, int N) {
    __shared__ int wsum[4];
    int t = threadIdx.x;
    int lane = t & 63, wv = t >> 6;
    int base = blockIdx.x * 1024 + t * 4;
    int s = 0;
#pragma unroll
    for (int j = 0; j < 4; ++j) {
        int i = base + j;
        if (i < N) s += deg[i];
    }
    for (int off = 1; off < 64; off <<= 1) s += __shfl_xor(s, off, 64);
    if (lane == 0) wsum[wv] = s;
    __syncthreads();
    if (t == 0) part[blockIdx.x] = wsum[0] + wsum[1] + wsum[2] + wsum[3];
}

__global__ void k_scan_mid(int* __restrict__ part, int nb) {
    __shared__ int buf[256];
    int t = threadIdx.x;
    buf[t] = (t < nb) ? part[t] : 0;
    __syncthreads();
    for (int off = 1; off < 256; off <<= 1) {
        int v = buf[t];
        int u = (t >= off) ? buf[t - off] : 0;
        __syncthreads();
        buf[t] = v + u;
        __syncthreads();
    }
    if (t < nb) part[t] = (t == 0) ? 0 : buf[t - 1];
}

__global__ __launch_bounds__(256) void k_scan_final(const int* __restrict__ deg,
                                                    const int* __restrict__ part,
                                                    int* __restrict__ out, int N) {
    __shared__ int wsum[4];
    int t = threadIdx.x;
    int lane = t & 63, wv = t >> 6;
    int base = blockIdx.x * 1024 + t * 4;
    int v[4];
    int s = 0;
#pragma unroll
    for (int j = 0; j < 4; ++j) {
        int i = base + j;
        v[j] = (i < N) ? deg[i] : 0;
        s += v[j];
    }
    int inc = s;
    for (int off = 1; off < 64; off <<= 1) {
        int u = __shfl_up(inc, off, 64);
        if (lane >= off) inc += u;
    }
    if (lane == 63) wsum[wv] = inc;
    __syncthreads();
    int excl = part[blockIdx.x] + inc - s;
    for (int w = 0; w < wv; ++w) excl += wsum[w];
#pragma unroll
    for (int j = 0; j < 4; ++j) {
        int i = base + j;
        if (i < N) {
            out[i] = excl;
            excl += v[j];
            if (i == N - 1) out[N] = excl;
        }
    }
}

// ---------- pass B: partition edges into bucket-contiguous regions ----------
__global__ __launch_bounds__(256) void k_partition(const int* __restrict__ src,
                                                   const int* __restrict__ dst, int E,
                                                   int nPB, const int* __restrict__ bscan,
                                                   unsigned* __restrict__ part_edges, int NB) {
    __shared__ int cur[256];
    int t = threadIdx.x;
    int blk = blockIdx.x;
    if (t < NB) cur[t] = bscan[t * nPB + blk];
    __syncthreads();
    int hi = min((blk + 1) * CHB, E);
    for (int e = blk * CHB + t; e < hi; e += 256) {
        int d = dst[e];
        int s = src[e];
        int pos = atomicAdd(&cur[d >> 9], 1);
        part_edges[pos] = ((unsigned)(d & 511) << 17) | (unsigned)s;
    }
}

// ---------- pass C: per-bucket counting sort -> row_ptr, dinv, ssrc ----------
__global__ __launch_bounds__(256) void k_bucket(const unsigned* __restrict__ part_edges,
                                                const int* __restrict__ bscan, int nPB,
                                                int N, int Npad, int* __restrict__ row_ptr,
                                                float* __restrict__ dinv,
                                                int* __restrict__ ssrc) {
    __shared__ int cnt[512];
    __shared__ int excl[512];
    __shared__ int wsum[4];
    int t = threadIdx.x;
    int b = blockIdx.x;
    int pb = bscan[b * nPB];
    int pe = bscan[(b + 1) * nPB];   // bscan[M] == E for the last bucket
    cnt[t] = 0; cnt[t + 256] = 0;
    __syncthreads();
    for (int e = pb + t; e < pe; e += 256)
        atomicAdd(&cnt[(part_edges[e] >> 17) & 511], 1);
    __syncthreads();
    int a0 = cnt[2 * t], a1 = cnt[2 * t + 1];
    int s = a0 + a1;
    int lane = t & 63, wv = t >> 6;
    int inc = s;
    for (int off = 1; off < 64; off <<= 1) {
        int u = __shfl_up(inc, off, 64);
        if (lane >= off) inc += u;
    }
    if (lane == 63) wsum[wv] = inc;
    __syncthreads();
    int pre = inc - s;
    for (int w = 0; w < wv; ++w) pre += wsum[w];
    excl[2 * t] = pre;
    excl[2 * t + 1] = pre + a0;
    int base = b << 9;
#pragma unroll
    for (int j = 0; j < 2; ++j) {
        int i = 2 * t + j;
        int g = base + i;
        int c = (j == 0) ? a0 : a1;
        int ex = (j == 0) ? pre : pre + a0;
        if (g < N) {
            row_ptr[g] = pb + ex;
            if (g == N - 1) row_ptr[N] = pb + ex + c;
        }
        if (g < Npad) dinv[g] = rsqrtf((float)c + 1.0f);
    }
    __syncthreads();
    for (int e = pb + t; e < pe; e += 256) {
        unsigned pk = part_edges[e];
        int doff = (pk >> 17) & 511;
        int pos = pb + atomicAdd(&excl[doff], 1);
        ssrc[pos] = (int)(pk & 0x1FFFFu);
    }
}

// W [K=128][realCols] f32 row-major -> fragment layout bf16:
// Wf[((kk*NT + n)*64 + lane)*8 + j] = W[kk*32 + (lane>>4)*8 + j][n*16 + (lane&15)]
__global__ void k_wfrag(const float* __restrict__ W, unsigned short* __restrict__ Wf,
                        int Ncol, int realCols) {
    int NT = Ncol >> 4;
    int total = 4 * NT * 64 * 8;
    int idx = blockIdx.x * blockDim.x + threadIdx.x;
    if (idx >= total) return;
    int j = idx & 7;
    int l = (idx >> 3) & 63;
    int t = idx >> 9;          // kk*NT + n
    int n = t % NT;
    int kk = t / NT;
    int k = kk * 32 + ((l >> 4) << 3) + j;
    int c = (n << 4) + (l & 15);
    float v = (c < realCols) ? W[k * realCols + c] : 0.0f;
    Wf[idx] = f2bf(v);
}

// ---------- layer-1 GEMM with fused f32->bf16 A conversion ----------
// H'[Npad][128] = dinv[row] * (bf16(X[N][128]) @ W1)
__global__ __launch_bounds__(256) void k_gemm_f32(const float* __restrict__ X,
                                                  const unsigned short* __restrict__ Wf,
                                                  const float* __restrict__ dinv,
                                                  unsigned short* __restrict__ Hout, int N) {
    int lane = threadIdx.x & 63;
    int wv = threadIdx.x >> 6;
    size_t row0 = (size_t)(blockIdx.x * 4 + wv) * 16;
    int arowi = (int)row0 + (lane & 15);
    const float* arow = X + (size_t)arowi * 128 + ((lane >> 4) << 3);
    bool vr = arowi < N;
    f32x4 acc[8];
#pragma unroll
    for (int n = 0; n < 8; ++n) acc[n] = (f32x4){0.f, 0.f, 0.f, 0.f};
#pragma unroll
    for (int kk = 0; kk < 4; ++kk) {
        union { bf16x8 v; unsigned short u[8]; } A;
        if (vr) {
            float4 f0 = *(const float4*)(arow + kk * 32);
            float4 f1 = *(const float4*)(arow + kk * 32 + 4);
            A.u[0] = f2bf(f0.x); A.u[1] = f2bf(f0.y);
            A.u[2] = f2bf(f0.z); A.u[3] = f2bf(f0.w);
            A.u[4] = f2bf(f1.x); A.u[5] = f2bf(f1.y);
            A.u[6] = f2bf(f1.z); A.u[7] = f2bf(f1.w);
        } else {
#pragma unroll
            for (int j = 0; j < 8; ++j) A.u[j] = 0;
        }
#pragma unroll
        for (int n = 0; n < 8; ++n) {
            bf16x8 b = *(const bf16x8*)(Wf + (((kk * 8 + n) * 64 + lane) << 3));
            acc[n] = __builtin_amdgcn_mfma_f32_16x16x32_bf16(A.v, b, acc[n], 0, 0, 0);
        }
    }
    size_t crow = row0 + ((lane >> 4) << 2);
    int ccol = lane & 15;
    float dv[4];
#pragma unroll
    for (int q = 0; q < 4; ++q) dv[q] = dinv[crow + q];
#pragma unroll
    for (int n = 0; n < 8; ++n) {
#pragma unroll
        for (int q = 0; q < 4; ++q) {
            Hout[(crow + q) * 128 + n * 16 + ccol] = f2bf(acc[n][q] * dv[q]);
        }
    }
}

// ---------- fused aggregation + GEMM ----------
// Phase A: each wave aggregates 16 nodes (one at a time, R7 structure:
//   4x16-lane groups split the edges, dwordx4 gathers, cross-group reduce),
//   writes relu(dinv*sum + b) rows as bf16 into a 64x(256+16)B LDS tile.
// Phase B: 64-row MFMA GEMM with A-fragments read from LDS.
// Out[row] = dinv[row] * (ab_row @ W), ab never touches global memory.
template<int NT>
__global__ __launch_bounds__(256) void k_agg_gemm(const unsigned short* __restrict__ H,
                                                  const int* __restrict__ row_ptr,
                                                  const int* __restrict__ ssrc,
                                                  const float* __restrict__ dinv,
                                                  const float* __restrict__ bias,
                                                  const unsigned short* __restrict__ Wf,
                                                  unsigned short* __restrict__ Hout, int N) {
    __shared__ uint4 lds[64 * LDSROW];
    int lane = threadIdx.x & 63;
    int wv = threadIdx.x >> 6;
    int g = lane >> 4;
    int c16 = lane & 15;
    unsigned sel_lo = SEL_LO, sel_hi = SEL_HI;
    const uint4* Hv = (const uint4*)H;
    const int iBase = blockIdx.x * 64 + wv * 16;

    // ---- phase A: aggregate 16 nodes per wave ----
    for (int ii = 0; ii < 16; ++ii) {
        int i = iBase + ii;
        float acc[8];
#pragma unroll
        for (int c = 0; c < 8; ++c) acc[c] = 0.f;
        if (i < N) {
            if (g == 0) {   // self row, counted once
                uint4 v = Hv[((size_t)i << 4) + c16];
                DOT8(v);
            }
            int e0 = row_ptr[i], e1 = row_ptr[i + 1];
            for (int base = e0; base < e1; base += 64) {
                int cnt = min(64, e1 - base);
                int sidx = (lane < cnt) ? ssrc[base + lane] : 0;
                int full = cnt & ~3;
#pragma unroll 4
                for (int j = 0; j < full; j += 4) {
                    int s = __shfl(sidx, j + g, 64);
                    uint4 v = Hv[((size_t)s << 4) + c16];
                    DOT8(v);
                }
                int jj = full + g;
                if (jj < cnt) {
                    int s = __shfl(sidx, jj, 64);
                    uint4 v = Hv[((size_t)s << 4) + c16];
                    DOT8(v);
                }
            }
        }
#pragma unroll
        for (int c = 0; c < 8; ++c) {
            acc[c] += __shfl_xor(acc[c], 16, 64);
            acc[c] += __shfl_xor(acc[c], 32, 64);
        }
        if (g == 0) {
            float dv = dinv[i];
            const float4* bv = (const float4*)bias;
            float4 b0 = bv[c16 * 2], b1 = bv[c16 * 2 + 1];
            float r0 = fmaxf(acc[0] * dv + b0.x, 0.f);
            float r1 = fmaxf(acc[1] * dv + b0.y, 0.f);
            float r2 = fmaxf(acc[2] * dv + b0.z, 0.f);
            float r3 = fmaxf(acc[3] * dv + b0.w, 0.f);
            float r4 = fmaxf(acc[4] * dv + b1.x, 0.f);
            float r5 = fmaxf(acc[5] * dv + b1.y, 0.f);
            float r6 = fmaxf(acc[6] * dv + b1.z, 0.f);
            float r7 = fmaxf(acc[7] * dv + b1.w, 0.f);
            uint4 o;
            o.x = (unsigned)f2bf(r0) | ((unsigned)f2bf(r1) << 16);
            o.y = (unsigned)f2bf(r2) | ((unsigned)f2bf(r3) << 16);
            o.z = (unsigned)f2bf(r4) | ((unsigned)f2bf(r5) << 16);
            o.w = (unsigned)f2bf(r6) | ((unsigned)f2bf(r7) << 16);
            lds[(wv * 16 + ii) * LDSROW + c16] = o;
        }
    }
    __syncthreads();

    // ---- phase B: 64-row GEMM, A from LDS ----
    f32x4 gacc[NT];
#pragma unroll
    for (int n = 0; n < NT; ++n) gacc[n] = (f32x4){0.f, 0.f, 0.f, 0.f};
    const uint4* arow = &lds[(wv * 16 + (lane & 15)) * LDSROW];
#pragma unroll
    for (int kk = 0; kk < 4; ++kk) {
        union { bf16x8 v; uint4 q; } A;
        A.q = arow[kk * 4 + (lane >> 4)];
#pragma unroll
        for (int n = 0; n < NT; ++n) {
            bf16x8 b = *(const bf16x8*)(Wf + (((kk * NT + n) * 64 + lane) << 3));
            gacc[n] = __builtin_amdgcn_mfma_f32_16x16x32_bf16(A.v, b, gacc[n], 0, 0, 0);
        }
    }
    const int NCOL = NT * 16;
    size_t row0 = (size_t)iBase;
    size_t crow = row0 + ((lane >> 4) << 2);
    int ccol = lane & 15;
    float dv[4];
#pragma unroll
    for (int q = 0; q < 4; ++q) dv[q] = dinv[crow + q];
#pragma unroll
    for (int n = 0; n < NT; ++n) {
#pragma unroll
        for (int q = 0; q < 4; ++q) {
            Hout[(crow + q) * NCOL + n * 16 + ccol] = f2bf(gacc[n][q] * dv[q]);
        }
    }
}

// ---------- final aggregation (64ch padded, Cout real) + bias + log_softmax ----------
// 4 groups x 16 lanes, dwordx2 (4 ch/lane); after reduce, redistribute so lane L
// owns channel L (4 shfl + 3 selects), then scalar 64-lane softmax (1 exp/lane).
__global__ __launch_bounds__(256) void k_agg3(const unsigned short* __restrict__ H,
                                              const int* __restrict__ row_ptr,
                                              const int* __restrict__ ssrc,
                                              const float* __restrict__ dinv,
                                              const float* __restrict__ b3,
                                              float* __restrict__ Out, int N, int Cout) {
    int lane = threadIdx.x & 63;
    int i = blockIdx.x * 4 + (threadIdx.x >> 6);
    if (i >= N) return;
    unsigned sel_lo = SEL_LO, sel_hi = SEL_HI;
    int g = lane >> 4;
    int c16 = lane & 15;                    // 8B chunk within the 128B row
    const uint2* Hv = (const uint2*)H;      // row i = 16 uint2
    float acc[4];
#pragma unroll
    for (int c = 0; c < 4; ++c) acc[c] = 0.f;
    int e0 = row_ptr[i], e1 = row_ptr[i + 1];
    for (int base = e0; base < e1; base += 64) {
        int cnt = min(64, e1 - base);
        int sidx = (lane < cnt) ? ssrc[base + lane] : 0;
        int full = cnt & ~3;
#pragma unroll 4
        for (int j = 0; j < full; j += 4) {
            int s = __shfl(sidx, j + g, 64);
            uint2 v = Hv[((size_t)s << 4) + c16];
            DOT4(v);
        }
        int jj = full + g;
        if (jj < cnt) {
            int s = __shfl(sidx, jj, 64);
            uint2 v = Hv[((size_t)s << 4) + c16];
            DOT4(v);
        }
    }
    if (g == 0) {
        uint2 v = Hv[((size_t)i << 4) + c16];
        DOT4(v);
    }
#pragma unroll
    for (int c = 0; c < 4; ++c) {
        acc[c] += __shfl_xor(acc[c], 16, 64);
        acc[c] += __shfl_xor(acc[c], 32, 64);
    }
    // redistribute: lane L <- element (L&3) of lane (L>>2)'s acc
    float t0 = __shfl(acc[0], lane >> 2, 64);
    float t1 = __shfl(acc[1], lane >> 2, 64);
    float t2 = __shfl(acc[2], lane >> 2, 64);
    float t3 = __shfl(acc[3], lane >> 2, 64);
    float a01 = (lane & 1) ? t1 : t0;
    float a23 = (lane & 1) ? t3 : t2;
    float av  = (lane & 2) ? a23 : a01;
    float dv = dinv[i];
    float z = (lane < Cout) ? av * dv + b3[lane] : -1e30f;
    float m = z;
    for (int off = 32; off; off >>= 1) m = fmaxf(m, __shfl_xor(m, off, 64));
    float pexp = (lane < Cout) ? expf(z - m) : 0.f;
    float ssum = pexp;
    for (int off = 32; off; off >>= 1) ssum += __shfl_xor(ssum, off, 64);
    if (lane < Cout) Out[(size_t)i * Cout + lane] = z - m - logf(ssum);
}

extern "C" void kernel_launch(void* const* d_in, const int* in_sizes, int n_in,
                              void* d_out, int out_size, void* d_ws, size_t ws_size,
                              hipStream_t stream) {
    const float* x  = (const float*)d_in[0];
    const int*   ei = (const int*)d_in[1];
    const float* W1 = (const float*)d_in[2];
    const float* b1 = (const float*)d_in[3];
    const float* W2 = (const float*)d_in[4];
    const float* b2 = (const float*)d_in[5];
    const float* W3 = (const float*)d_in[6];
    const float* b3 = (const float*)d_in[7];

    const int N = in_sizes[0] / 128;
    const int E = in_sizes[1] / 2;
    const int Cout = in_sizes[7];       // 47
    const int Npad = (N + 63) & ~63;
    const int* srcp = ei;
    const int* dstp = ei + E;

    const int NB  = (N + 511) >> 9;             // coarse buckets (196), must be <= 256
    const int nPB = (E + CHB - 1) / CHB;        // partition blocks (196)
    const int M   = NB * nPB;                   // bhist size (38416)

    // ---- workspace partition (256B aligned) ----
    char* p = (char*)d_ws;
    auto alloc = [&](size_t bytes) -> void* {
        void* r = (void*)p;
        p += (bytes + 255) & ~(size_t)255;
        return r;
    };
    float* dinv     = (float*)alloc((size_t)Npad * 4);
    int*   row_ptr  = (int*)alloc((size_t)(N + 1) * 4);
    int*   bhist    = (int*)alloc((size_t)M * 4);
    int*   bscan    = (int*)alloc((size_t)(M + 1) * 4);
    int*   part     = (int*)alloc(1024 * 4);
    unsigned* pedge = (unsigned*)alloc((size_t)E * 4);
    int*   ssrc     = (int*)alloc((size_t)E * 4);
    unsigned short* hb  = (unsigned short*)alloc((size_t)Npad * 128 * 2);
    unsigned short* ab  = (unsigned short*)alloc((size_t)Npad * 128 * 2);
    unsigned short* wf1 = (unsigned short*)alloc(128 * 128 * 2);
    unsigned short* wf2 = (unsigned short*)alloc(128 * 128 * 2);
    unsigned short* wf3 = (unsigned short*)alloc(128 * 64 * 2);

    // ---- CSR build: hist -> scan -> partition -> per-bucket counting sort ----
    const int nb2 = (M + 1023) / 1024;          // 38 blocks (<= 256)
    k_hist<<<nPB, 256, 0, stream>>>(dstp, E, nPB, bhist, NB);
    k_scan_part<<<nb2, 256, 0, stream>>>(bhist, part, M);
    k_scan_mid<<<1, 256, 0, stream>>>(part, nb2);
    k_scan_final<<<nb2, 256, 0, stream>>>(bhist, part, bscan, M);
    k_partition<<<nPB, 256, 0, stream>>>(srcp, dstp, E, nPB, bscan, pedge, NB);
    k_bucket<<<NB, 256, 0, stream>>>(pedge, bscan, nPB, N, Npad, row_ptr, dinv, ssrc);

    // weight fragment conversions
    k_wfrag<<<(16384 + 255) / 256, 256, 0, stream>>>(W1, wf1, 128, 128);
    k_wfrag<<<(16384 + 255) / 256, 256, 0, stream>>>(W2, wf2, 128, 128);
    k_wfrag<<<(8192 + 255) / 256, 256, 0, stream>>>(W3, wf3, 64, Cout);

    const int gemmGrid = Npad / 64;
    const int aggGrid = (N + 3) / 4;

    // layer 1 GEMM (fused f32->bf16 conversion of x)
    k_gemm_f32<<<gemmGrid, 256, 0, stream>>>(x, wf1, dinv, hb, N);
    // agg1 + GEMM2 fused
    k_agg_gemm<8><<<gemmGrid, 256, 0, stream>>>(hb, row_ptr, ssrc, dinv, b1, wf2, ab, N);
    // agg2 + GEMM3 fused (output 64 padded cols)
    k_agg_gemm<4><<<gemmGrid, 256, 0, stream>>>(ab, row_ptr, ssrc, dinv, b2, wf3, hb, N);
    // agg3 + bias + log_softmax
    k_agg3<<<aggGrid, 256, 0, stream>>>(hb, row_ptr, ssrc, dinv, b3,
                                        (float*)d_out, N, Cout);
}

// Round 10
// 292.976 us; speedup vs baseline: 1.1089x; 1.1089x over previous
//
#include <hip/hip_runtime.h>
#include <stdint.h>

typedef __bf16 bf16x8 __attribute__((ext_vector_type(8)));
typedef float f32x4 __attribute__((ext_vector_type(4)));

#define CHB 8192  // edges per partition block

__device__ __forceinline__ unsigned short f2bf(float f) {
    union { float f; unsigned u; } x; x.f = f;
    unsigned r = x.u + 0x7fffu + ((x.u >> 16) & 1u);
    return (unsigned short)(r >> 16);
}

// acc += pk.bf16[0]*sel.bf16[0] + pk.bf16[1]*sel.bf16[1]  (one VOP3P op)
__device__ __forceinline__ void dot2acc(float& a, unsigned pk, unsigned sel) {
    asm("v_dot2_f32_bf16 %0, %1, %2, %0" : "+v"(a) : "v"(pk), "v"(sel));
}

// selector constants: bf16 pair (1.0, 0.0) and (0.0, 1.0)
#define SEL_LO 0x00003F80u
#define SEL_HI 0x3F800000u

#define DOT8(v)                                      \
    dot2acc(acc[0], (v).x, sel_lo); dot2acc(acc[1], (v).x, sel_hi); \
    dot2acc(acc[2], (v).y, sel_lo); dot2acc(acc[3], (v).y, sel_hi); \
    dot2acc(acc[4], (v).z, sel_lo); dot2acc(acc[5], (v).z, sel_hi); \
    dot2acc(acc[6], (v).w, sel_lo); dot2acc(acc[7], (v).w, sel_hi);

#define DOT4(v)                                      \
    dot2acc(acc[0], (v).x, sel_lo); dot2acc(acc[1], (v).x, sel_hi); \
    dot2acc(acc[2], (v).y, sel_lo); dot2acc(acc[3], (v).y, sel_hi);

// ---------- pass A: per-(bucket,block) histogram. bucket = dst>>9 ----------
__global__ __launch_bounds__(256) void k_hist(const int* __restrict__ dst, int E, int nPB,
                                              int* __restrict__ bhist, int NB) {
    __shared__ int h[256];
    int t = threadIdx.x;
    h[t] = 0;
    __syncthreads();
    int blk = blockIdx.x;
    int hi = min((blk + 1) * CHB, E);
    for (int e = blk * CHB + t; e < hi; e += 256) atomicAdd(&h[dst[e] >> 9], 1);
    __syncthreads();
    if (t < NB) bhist[t * nPB + blk] = h[t];
}

// ---------- hierarchical scan (generic): in[M] -> out[M+1] exclusive ----------
__global__ __launch_bounds__(256) void k_scan_part(const int* __restrict__ deg,
                                                   int* __restrict__ part, int N) {
    __shared__ int wsum[4];
    int t = threadIdx.x;
    int lane = t & 63, wv = t >> 6;
    int base = blockIdx.x * 1024 + t * 4;
    int s = 0;
#pragma unroll
    for (int j = 0; j < 4; ++j) {
        int i = base + j;
        if (i < N) s += deg[i];
    }
    for (int off = 1; off < 64; off <<= 1) s += __shfl_xor(s, off, 64);
    if (lane == 0) wsum[wv] = s;
    __syncthreads();
    if (t == 0) part[blockIdx.x] = wsum[0] + wsum[1] + wsum[2] + wsum[3];
}

__global__ void k_scan_mid(int* __restrict__ part, int nb) {
    __shared__ int buf[256];
    int t = threadIdx.x;
    buf[t] = (t < nb) ? part[t] : 0;
    __syncthreads();
    for (int off = 1; off < 256; off <<= 1) {
        int v = buf[t];
        int u = (t >= off) ? buf[t - off] : 0;
        __syncthreads();
        buf[t] = v + u;
        __syncthreads();
    }
    if (t < nb) part[t] = (t == 0) ? 0 : buf[t - 1];
}

__global__ __launch_bounds__(256) void k_scan_final(const int* __restrict__ deg,
                                                    const int* __restrict__ part,
                                                    int* __restrict__ out, int N) {
    __shared__ int wsum[4];
    int t = threadIdx.x;
    int lane = t & 63, wv = t >> 6;
    int base = blockIdx.x * 1024 + t * 4;
    int v[4];
    int s = 0;
#pragma unroll
    for (int j = 0; j < 4; ++j) {
        int i = base + j;
        v[j] = (i < N) ? deg[i] : 0;
        s += v[j];
    }
    int inc = s;
    for (int off = 1; off < 64; off <<= 1) {
        int u = __shfl_up(inc, off, 64);
        if (lane >= off) inc += u;
    }
    if (lane == 63) wsum[wv] = inc;
    __syncthreads();
    int excl = part[blockIdx.x] + inc - s;
    for (int w = 0; w < wv; ++w) excl += wsum[w];
#pragma unroll
    for (int j = 0; j < 4; ++j) {
        int i = base + j;
        if (i < N) {
            out[i] = excl;
            excl += v[j];
            if (i == N - 1) out[N] = excl;
        }
    }
}

// ---------- pass B: partition edges into bucket-contiguous regions ----------
__global__ __launch_bounds__(256) void k_partition(const int* __restrict__ src,
                                                   const int* __restrict__ dst, int E,
                                                   int nPB, const int* __restrict__ bscan,
                                                   unsigned* __restrict__ part_edges, int NB) {
    __shared__ int cur[256];
    int t = threadIdx.x;
    int blk = blockIdx.x;
    if (t < NB) cur[t] = bscan[t * nPB + blk];
    __syncthreads();
    int hi = min((blk + 1) * CHB, E);
    for (int e = blk * CHB + t; e < hi; e += 256) {
        int d = dst[e];
        int s = src[e];
        int pos = atomicAdd(&cur[d >> 9], 1);
        part_edges[pos] = ((unsigned)(d & 511) << 17) | (unsigned)s;
    }
}

// ---------- pass C: per-bucket counting sort -> row_ptr, dinv, ssrc ----------
__global__ __launch_bounds__(256) void k_bucket(const unsigned* __restrict__ part_edges,
                                                const int* __restrict__ bscan, int nPB,
                                                int N, int Npad, int* __restrict__ row_ptr,
                                                float* __restrict__ dinv,
                                                int* __restrict__ ssrc) {
    __shared__ int cnt[512];
    __shared__ int excl[512];
    __shared__ int wsum[4];
    int t = threadIdx.x;
    int b = blockIdx.x;
    int pb = bscan[b * nPB];
    int pe = bscan[(b + 1) * nPB];   // bscan[M] == E for the last bucket
    cnt[t] = 0; cnt[t + 256] = 0;
    __syncthreads();
    for (int e = pb + t; e < pe; e += 256)
        atomicAdd(&cnt[(part_edges[e] >> 17) & 511], 1);
    __syncthreads();
    int a0 = cnt[2 * t], a1 = cnt[2 * t + 1];
    int s = a0 + a1;
    int lane = t & 63, wv = t >> 6;
    int inc = s;
    for (int off = 1; off < 64; off <<= 1) {
        int u = __shfl_up(inc, off, 64);
        if (lane >= off) inc += u;
    }
    if (lane == 63) wsum[wv] = inc;
    __syncthreads();
    int pre = inc - s;
    for (int w = 0; w < wv; ++w) pre += wsum[w];
    excl[2 * t] = pre;
    excl[2 * t + 1] = pre + a0;
    int base = b << 9;
#pragma unroll
    for (int j = 0; j < 2; ++j) {
        int i = 2 * t + j;
        int g = base + i;
        int c = (j == 0) ? a0 : a1;
        int ex = (j == 0) ? pre : pre + a0;
        if (g < N) {
            row_ptr[g] = pb + ex;
            if (g == N - 1) row_ptr[N] = pb + ex + c;
        }
        if (g < Npad) dinv[g] = rsqrtf((float)c + 1.0f);
    }
    __syncthreads();
    for (int e = pb + t; e < pe; e += 256) {
        unsigned pk = part_edges[e];
        int doff = (pk >> 17) & 511;
        int pos = pb + atomicAdd(&excl[doff], 1);
        ssrc[pos] = (int)(pk & 0x1FFFFu);
    }
}

// ---------- all three weight matrices -> fragment layout, one launch ----------
__device__ __forceinline__ void wfrag_one(const float* W, unsigned short* Wf, int idx,
                                          int NT, int realCols) {
    int j = idx & 7;
    int l = (idx >> 3) & 63;
    int t = idx >> 9;          // kk*NT + n
    int n = t % NT;
    int kk = t / NT;
    int k = kk * 32 + ((l >> 4) << 3) + j;
    int c = (n << 4) + (l & 15);
    float v = (c < realCols) ? W[k * realCols + c] : 0.0f;
    Wf[idx] = f2bf(v);
}

__global__ void k_wfrag_all(const float* __restrict__ W1, const float* __restrict__ W2,
                            const float* __restrict__ W3,
                            unsigned short* __restrict__ wf1,
                            unsigned short* __restrict__ wf2,
                            unsigned short* __restrict__ wf3, int Cout) {
    int idx = blockIdx.x * blockDim.x + threadIdx.x;
    if (idx < 16384) wfrag_one(W1, wf1, idx, 8, 128);
    else if (idx < 32768) wfrag_one(W2, wf2, idx - 16384, 8, 128);
    else if (idx < 40960) wfrag_one(W3, wf3, idx - 32768, 4, Cout);
}

// ---------- layer-1 GEMM with fused f32->bf16 A conversion ----------
// H'[Npad][128] = dinv[row] * (bf16(X[N][128]) @ W1)
__global__ __launch_bounds__(256) void k_gemm_f32(const float* __restrict__ X,
                                                  const unsigned short* __restrict__ Wf,
                                                  const float* __restrict__ dinv,
                                                  unsigned short* __restrict__ Hout, int N) {
    int lane = threadIdx.x & 63;
    int wv = threadIdx.x >> 6;
    size_t row0 = (size_t)(blockIdx.x * 4 + wv) * 16;
    int arowi = (int)row0 + (lane & 15);
    const float* arow = X + (size_t)arowi * 128 + ((lane >> 4) << 3);
    bool vr = arowi < N;
    f32x4 acc[8];
#pragma unroll
    for (int n = 0; n < 8; ++n) acc[n] = (f32x4){0.f, 0.f, 0.f, 0.f};
#pragma unroll
    for (int kk = 0; kk < 4; ++kk) {
        union { bf16x8 v; unsigned short u[8]; } A;
        if (vr) {
            float4 f0 = *(const float4*)(arow + kk * 32);
            float4 f1 = *(const float4*)(arow + kk * 32 + 4);
            A.u[0] = f2bf(f0.x); A.u[1] = f2bf(f0.y);
            A.u[2] = f2bf(f0.z); A.u[3] = f2bf(f0.w);
            A.u[4] = f2bf(f1.x); A.u[5] = f2bf(f1.y);
            A.u[6] = f2bf(f1.z); A.u[7] = f2bf(f1.w);
        } else {
#pragma unroll
            for (int j = 0; j < 8; ++j) A.u[j] = 0;
        }
#pragma unroll
        for (int n = 0; n < 8; ++n) {
            bf16x8 b = *(const bf16x8*)(Wf + (((kk * 8 + n) * 64 + lane) << 3));
            acc[n] = __builtin_amdgcn_mfma_f32_16x16x32_bf16(A.v, b, acc[n], 0, 0, 0);
        }
    }
    size_t crow = row0 + ((lane >> 4) << 2);
    int ccol = lane & 15;
    float dv[4];
#pragma unroll
    for (int q = 0; q < 4; ++q) dv[q] = dinv[crow + q];
#pragma unroll
    for (int n = 0; n < 8; ++n) {
#pragma unroll
        for (int q = 0; q < 4; ++q) {
            Hout[(crow + q) * 128 + n * 16 + ccol] = f2bf(acc[n][q] * dv[q]);
        }
    }
}

// ---------- GEMM (bf16 A): H'[Npad][NT*16] = dinv[row] * (A[Npad][128] @ W) ----------
template<int NT>
__global__ __launch_bounds__(256) void k_gemm(const unsigned short* __restrict__ A,
                                              const unsigned short* __restrict__ Wf,
                                              const float* __restrict__ dinv,
                                              unsigned short* __restrict__ Hout) {
    int lane = threadIdx.x & 63;
    int wv = threadIdx.x >> 6;
    int rb = blockIdx.x * 4 + wv;
    size_t row0 = (size_t)rb * 16;
    const unsigned short* arow = A + (row0 + (lane & 15)) * 128 + ((lane >> 4) << 3);
    f32x4 acc[NT];
#pragma unroll
    for (int n = 0; n < NT; ++n) acc[n] = (f32x4){0.f, 0.f, 0.f, 0.f};
#pragma unroll
    for (int kk = 0; kk < 4; ++kk) {
        bf16x8 a = *(const bf16x8*)(arow + kk * 32);
#pragma unroll
        for (int n = 0; n < NT; ++n) {
            bf16x8 b = *(const bf16x8*)(Wf + (((kk * NT + n) * 64 + lane) << 3));
            acc[n] = __builtin_amdgcn_mfma_f32_16x16x32_bf16(a, b, acc[n], 0, 0, 0);
        }
    }
    const int NCOL = NT * 16;
    size_t crow = row0 + ((lane >> 4) << 2);
    int ccol = lane & 15;
    float dv[4];
#pragma unroll
    for (int q = 0; q < 4; ++q) dv[q] = dinv[crow + q];
#pragma unroll
    for (int n = 0; n < NT; ++n) {
#pragma unroll
        for (int q = 0; q < 4; ++q) {
            Hout[(crow + q) * NCOL + n * 16 + ccol] = f2bf(acc[n][q] * dv[q]);
        }
    }
}

// ---------- aggregation (128 ch): one wave per dst node ----------
// 4 groups x 16 lanes; group g gathers edge (j+g) with dwordx4 (8 ch/lane);
// dot2-based accumulate; cross-group shfl_xor reduce at the end.
__global__ __launch_bounds__(256) void k_agg(const unsigned short* __restrict__ H,
                                             const int* __restrict__ row_ptr,
                                             const int* __restrict__ ssrc,
                                             const float* __restrict__ dinv,
                                             const float* __restrict__ bias,
                                             unsigned short* __restrict__ Out, int N) {
    int lane = threadIdx.x & 63;
    int i = blockIdx.x * 4 + (threadIdx.x >> 6);
    if (i >= N) return;
    unsigned sel_lo = SEL_LO, sel_hi = SEL_HI;
    int g = lane >> 4;
    int c16 = lane & 15;                    // 16B chunk within the 256B row
    const uint4* Hv = (const uint4*)H;      // row i = 16 uint4
    float acc[8];
#pragma unroll
    for (int c = 0; c < 8; ++c) acc[c] = 0.f;
    int e0 = row_ptr[i], e1 = row_ptr[i + 1];
    for (int base = e0; base < e1; base += 64) {
        int cnt = min(64, e1 - base);
        int sidx = (lane < cnt) ? ssrc[base + lane] : 0;
        int full = cnt & ~3;
#pragma unroll 4
        for (int j = 0; j < full; j += 4) {
            int s = __shfl(sidx, j + g, 64);
            uint4 v = Hv[((size_t)s << 4) + c16];
            DOT8(v);
        }
        int jj = full + g;
        if (jj < cnt) {
            int s = __shfl(sidx, jj, 64);
            uint4 v = Hv[((size_t)s << 4) + c16];
            DOT8(v);
        }
    }
    if (g == 0) {   // self row, added exactly once
        uint4 v = Hv[((size_t)i << 4) + c16];
        DOT8(v);
    }
#pragma unroll
    for (int c = 0; c < 8; ++c) {
        acc[c] += __shfl_xor(acc[c], 16, 64);
        acc[c] += __shfl_xor(acc[c], 32, 64);
    }
    if (g == 0) {
        float dv = dinv[i];
        const float4* bv = (const float4*)bias;
        float4 b0 = bv[c16 * 2], b1 = bv[c16 * 2 + 1];
        float r0 = fmaxf(acc[0] * dv + b0.x, 0.f);
        float r1 = fmaxf(acc[1] * dv + b0.y, 0.f);
        float r2 = fmaxf(acc[2] * dv + b0.z, 0.f);
        float r3 = fmaxf(acc[3] * dv + b0.w, 0.f);
        float r4 = fmaxf(acc[4] * dv + b1.x, 0.f);
        float r5 = fmaxf(acc[5] * dv + b1.y, 0.f);
        float r6 = fmaxf(acc[6] * dv + b1.z, 0.f);
        float r7 = fmaxf(acc[7] * dv + b1.w, 0.f);
        uint4 o;
        o.x = (unsigned)f2bf(r0) | ((unsigned)f2bf(r1) << 16);
        o.y = (unsigned)f2bf(r2) | ((unsigned)f2bf(r3) << 16);
        o.z = (unsigned)f2bf(r4) | ((unsigned)f2bf(r5) << 16);
        o.w = (unsigned)f2bf(r6) | ((unsigned)f2bf(r7) << 16);
        ((uint4*)Out)[((size_t)i << 4) + c16] = o;
    }
}

// ---------- final aggregation (64ch padded, Cout real) + bias + log_softmax ----------
// 4 groups x 16 lanes, dwordx2 (4 ch/lane); after reduce, redistribute so lane L
// owns channel L (4 shfl + 3 selects), then scalar 64-lane softmax (1 exp/lane).
__global__ __launch_bounds__(256) void k_agg3(const unsigned short* __restrict__ H,
                                              const int* __restrict__ row_ptr,
                                              const int* __restrict__ ssrc,
                                              const float* __restrict__ dinv,
                                              const float* __restrict__ b3,
                                              float* __restrict__ Out, int N, int Cout) {
    int lane = threadIdx.x & 63;
    int i = blockIdx.x * 4 + (threadIdx.x >> 6);
    if (i >= N) return;
    unsigned sel_lo = SEL_LO, sel_hi = SEL_HI;
    int g = lane >> 4;
    int c16 = lane & 15;                    // 8B chunk within the 128B row
    const uint2* Hv = (const uint2*)H;      // row i = 16 uint2
    float acc[4];
#pragma unroll
    for (int c = 0; c < 4; ++c) acc[c] = 0.f;
    int e0 = row_ptr[i], e1 = row_ptr[i + 1];
    for (int base = e0; base < e1; base += 64) {
        int cnt = min(64, e1 - base);
        int sidx = (lane < cnt) ? ssrc[base + lane] : 0;
        int full = cnt & ~3;
#pragma unroll 4
        for (int j = 0; j < full; j += 4) {
            int s = __shfl(sidx, j + g, 64);
            uint2 v = Hv[((size_t)s << 4) + c16];
            DOT4(v);
        }
        int jj = full + g;
        if (jj < cnt) {
            int s = __shfl(sidx, jj, 64);
            uint2 v = Hv[((size_t)s << 4) + c16];
            DOT4(v);
        }
    }
    if (g == 0) {
        uint2 v = Hv[((size_t)i << 4) + c16];
        DOT4(v);
    }
#pragma unroll
    for (int c = 0; c < 4; ++c) {
        acc[c] += __shfl_xor(acc[c], 16, 64);
        acc[c] += __shfl_xor(acc[c], 32, 64);
    }
    // redistribute: lane L <- element (L&3) of lane (L>>2)'s acc
    float t0 = __shfl(acc[0], lane >> 2, 64);
    float t1 = __shfl(acc[1], lane >> 2, 64);
    float t2 = __shfl(acc[2], lane >> 2, 64);
    float t3 = __shfl(acc[3], lane >> 2, 64);
    float a01 = (lane & 1) ? t1 : t0;
    float a23 = (lane & 1) ? t3 : t2;
    float av  = (lane & 2) ? a23 : a01;
    float dv = dinv[i];
    float z = (lane < Cout) ? av * dv + b3[lane] : -1e30f;
    float m = z;
    for (int off = 32; off; off >>= 1) m = fmaxf(m, __shfl_xor(m, off, 64));
    float pexp = (lane < Cout) ? expf(z - m) : 0.f;
    float ssum = pexp;
    for (int off = 32; off; off >>= 1) ssum += __shfl_xor(ssum, off, 64);
    if (lane < Cout) Out[(size_t)i * Cout + lane] = z - m - logf(ssum);
}

extern "C" void kernel_launch(void* const* d_in, const int* in_sizes, int n_in,
                              void* d_out, int out_size, void* d_ws, size_t ws_size,
                              hipStream_t stream) {
    const float* x  = (const float*)d_in[0];
    const int*   ei = (const int*)d_in[1];
    const float* W1 = (const float*)d_in[2];
    const float* b1 = (const float*)d_in[3];
    const float* W2 = (const float*)d_in[4];
    const float* b2 = (const float*)d_in[5];
    const float* W3 = (const float*)d_in[6];
    const float* b3 = (const float*)d_in[7];

    const int N = in_sizes[0] / 128;
    const int E = in_sizes[1] / 2;
    const int Cout = in_sizes[7];       // 47
    const int Npad = (N + 63) & ~63;
    const int* srcp = ei;
    const int* dstp = ei + E;

    const int NB  = (N + 511) >> 9;             // coarse buckets (196), must be <= 256
    const int nPB = (E + CHB - 1) / CHB;        // partition blocks (196)
    const int M   = NB * nPB;                   // bhist size (38416)

    // ---- workspace partition (256B aligned) ----
    char* p = (char*)d_ws;
    auto alloc = [&](size_t bytes) -> void* {
        void* r = (void*)p;
        p += (bytes + 255) & ~(size_t)255;
        return r;
    };
    float* dinv     = (float*)alloc((size_t)Npad * 4);
    int*   row_ptr  = (int*)alloc((size_t)(N + 1) * 4);
    int*   bhist    = (int*)alloc((size_t)M * 4);
    int*   bscan    = (int*)alloc((size_t)(M + 1) * 4);
    int*   part     = (int*)alloc(1024 * 4);
    unsigned* pedge = (unsigned*)alloc((size_t)E * 4);
    int*   ssrc     = (int*)alloc((size_t)E * 4);
    unsigned short* hb  = (unsigned short*)alloc((size_t)Npad * 128 * 2);
    unsigned short* ab  = (unsigned short*)alloc((size_t)Npad * 128 * 2);
    unsigned short* wf1 = (unsigned short*)alloc(128 * 128 * 2);
    unsigned short* wf2 = (unsigned short*)alloc(128 * 128 * 2);
    unsigned short* wf3 = (unsigned short*)alloc(128 * 64 * 2);

    // ---- CSR build: hist -> scan -> partition -> per-bucket counting sort ----
    const int nb2 = (M + 1023) / 1024;          // 38 blocks (<= 256)
    k_hist<<<nPB, 256, 0, stream>>>(dstp, E, nPB, bhist, NB);
    k_scan_part<<<nb2, 256, 0, stream>>>(bhist, part, M);
    k_scan_mid<<<1, 256, 0, stream>>>(part, nb2);
    k_scan_final<<<nb2, 256, 0, stream>>>(bhist, part, bscan, M);
    k_partition<<<nPB, 256, 0, stream>>>(srcp, dstp, E, nPB, bscan, pedge, NB);
    k_bucket<<<NB, 256, 0, stream>>>(pedge, bscan, nPB, N, Npad, row_ptr, dinv, ssrc);

    // weight fragment conversion (single launch for all 3)
    k_wfrag_all<<<160, 256, 0, stream>>>(W1, W2, W3, wf1, wf2, wf3, Cout);

    const int gemmGrid = Npad / 64;
    const int aggGrid = (N + 3) / 4;

    // layer 1 GEMM (fused f32->bf16 conversion of x)
    k_gemm_f32<<<gemmGrid, 256, 0, stream>>>(x, wf1, dinv, hb, N);
    k_agg<<<aggGrid, 256, 0, stream>>>(hb, row_ptr, ssrc, dinv, b1, ab, N);
    // layer 2
    k_gemm<8><<<gemmGrid, 256, 0, stream>>>(ab, wf2, dinv, hb);
    k_agg<<<aggGrid, 256, 0, stream>>>(hb, row_ptr, ssrc, dinv, b2, ab, N);
    // layer 3 (output padded to 64 cols) + log_softmax
    k_gemm<4><<<gemmGrid, 256, 0, stream>>>(ab, wf3, dinv, hb);
    k_agg3<<<aggGrid, 256, 0, stream>>>(hb, row_ptr, ssrc, dinv, b3,
                                        (float*)d_out, N, Cout);
}

// Round 11
// 292.765 us; speedup vs baseline: 1.1097x; 1.0007x over previous
//
#include <hip/hip_runtime.h>
#include <stdint.h>

typedef __bf16 bf16x8 __attribute__((ext_vector_type(8)));
typedef float f32x4 __attribute__((ext_vector_type(4)));

#define CHB 8192  // edges per partition block

__device__ __forceinline__ unsigned short f2bf(float f) {
    union { float f; unsigned u; } x; x.f = f;
    unsigned r = x.u + 0x7fffu + ((x.u >> 16) & 1u);
    return (unsigned short)(r >> 16);
}

// acc += pk.bf16[0]*sel.bf16[0] + pk.bf16[1]*sel.bf16[1]  (one VOP3P op)
__device__ __forceinline__ void dot2acc(float& a, unsigned pk, unsigned sel) {
    asm("v_dot2_f32_bf16 %0, %1, %2, %0" : "+v"(a) : "v"(pk), "v"(sel));
}

// selector constants: bf16 pair (1.0, 0.0) and (0.0, 1.0)
#define SEL_LO 0x00003F80u
#define SEL_HI 0x3F800000u

#define DOT8(v)                                      \
    dot2acc(acc[0], (v).x, sel_lo); dot2acc(acc[1], (v).x, sel_hi); \
    dot2acc(acc[2], (v).y, sel_lo); dot2acc(acc[3], (v).y, sel_hi); \
    dot2acc(acc[4], (v).z, sel_lo); dot2acc(acc[5], (v).z, sel_hi); \
    dot2acc(acc[6], (v).w, sel_lo); dot2acc(acc[7], (v).w, sel_hi);

#define DOT4(v)                                      \
    dot2acc(acc[0], (v).x, sel_lo); dot2acc(acc[1], (v).x, sel_hi); \
    dot2acc(acc[2], (v).y, sel_lo); dot2acc(acc[3], (v).y, sel_hi);

// ---------- pass A: per-(bucket,block) histogram. bucket = dst>>9 ----------
__global__ __launch_bounds__(256) void k_hist(const int* __restrict__ dst, int E, int nPB,
                                              int* __restrict__ bhist, int NB) {
    __shared__ int h[256];
    int t = threadIdx.x;
    h[t] = 0;
    __syncthreads();
    int blk = blockIdx.x;
    int hi = min((blk + 1) * CHB, E);
    for (int e = blk * CHB + t; e < hi; e += 256) atomicAdd(&h[dst[e] >> 9], 1);
    __syncthreads();
    if (t < NB) bhist[t * nPB + blk] = h[t];
}

// ---------- hierarchical scan (generic): in[M] -> out[M+1] exclusive ----------
__global__ __launch_bounds__(256) void k_scan_part(const int* __restrict__ deg,
                                                   int* __restrict__ part, int N) {
    __shared__ int wsum[4];
    int t = threadIdx.x;
    int lane = t & 63, wv = t >> 6;
    int base = blockIdx.x * 1024 + t * 4;
    int s = 0;
#pragma unroll
    for (int j = 0; j < 4; ++j) {
        int i = base + j;
        if (i < N) s += deg[i];
    }
    for (int off = 1; off < 64; off <<= 1) s += __shfl_xor(s, off, 64);
    if (lane == 0) wsum[wv] = s;
    __syncthreads();
    if (t == 0) part[blockIdx.x] = wsum[0] + wsum[1] + wsum[2] + wsum[3];
}

__global__ void k_scan_mid(int* __restrict__ part, int nb) {
    __shared__ int buf[256];
    int t = threadIdx.x;
    buf[t] = (t < nb) ? part[t] : 0;
    __syncthreads();
    for (int off = 1; off < 256; off <<= 1) {
        int v = buf[t];
        int u = (t >= off) ? buf[t - off] : 0;
        __syncthreads();
        buf[t] = v + u;
        __syncthreads();
    }
    if (t < nb) part[t] = (t == 0) ? 0 : buf[t - 1];
}

__global__ __launch_bounds__(256) void k_scan_final(const int* __restrict__ deg,
                                                    const int* __restrict__ part,
                                                    int* __restrict__ out, int N) {
    __shared__ int wsum[4];
    int t = threadIdx.x;
    int lane = t & 63, wv = t >> 6;
    int base = blockIdx.x * 1024 + t * 4;
    int v[4];
    int s = 0;
#pragma unroll
    for (int j = 0; j < 4; ++j) {
        int i = base + j;
        v[j] = (i < N) ? deg[i] : 0;
        s += v[j];
    }
    int inc = s;
    for (int off = 1; off < 64; off <<= 1) {
        int u = __shfl_up(inc, off, 64);
        if (lane >= off) inc += u;
    }
    if (lane == 63) wsum[wv] = inc;
    __syncthreads();
    int excl = part[blockIdx.x] + inc - s;
    for (int w = 0; w < wv; ++w) excl += wsum[w];
#pragma unroll
    for (int j = 0; j < 4; ++j) {
        int i = base + j;
        if (i < N) {
            out[i] = excl;
            excl += v[j];
            if (i == N - 1) out[N] = excl;
        }
    }
}

// ---------- pass B: partition edges into bucket-contiguous regions ----------
__global__ __launch_bounds__(256) void k_partition(const int* __restrict__ src,
                                                   const int* __restrict__ dst, int E,
                                                   int nPB, const int* __restrict__ bscan,
                                                   unsigned* __restrict__ part_edges, int NB) {
    __shared__ int cur[256];
    int t = threadIdx.x;
    int blk = blockIdx.x;
    if (t < NB) cur[t] = bscan[t * nPB + blk];
    __syncthreads();
    int hi = min((blk + 1) * CHB, E);
    for (int e = blk * CHB + t; e < hi; e += 256) {
        int d = dst[e];
        int s = src[e];
        int pos = atomicAdd(&cur[d >> 9], 1);
        part_edges[pos] = ((unsigned)(d & 511) << 17) | (unsigned)s;
    }
}

// ---------- pass C: per-bucket counting sort -> row_ptr, dinv, ssrc ----------
__global__ __launch_bounds__(256) void k_bucket(const unsigned* __restrict__ part_edges,
                                                const int* __restrict__ bscan, int nPB,
                                                int N, int Npad, int* __restrict__ row_ptr,
                                                float* __restrict__ dinv,
                                                int* __restrict__ ssrc) {
    __shared__ int cnt[512];
    __shared__ int excl[512];
    __shared__ int wsum[4];
    int t = threadIdx.x;
    int b = blockIdx.x;
    int pb = bscan[b * nPB];
    int pe = bscan[(b + 1) * nPB];   // bscan[M] == E for the last bucket
    cnt[t] = 0; cnt[t + 256] = 0;
    __syncthreads();
    for (int e = pb + t; e < pe; e += 256)
        atomicAdd(&cnt[(part_edges[e] >> 17) & 511], 1);
    __syncthreads();
    int a0 = cnt[2 * t], a1 = cnt[2 * t + 1];
    int s = a0 + a1;
    int lane = t & 63, wv = t >> 6;
    int inc = s;
    for (int off = 1; off < 64; off <<= 1) {
        int u = __shfl_up(inc, off, 64);
        if (lane >= off) inc += u;
    }
    if (lane == 63) wsum[wv] = inc;
    __syncthreads();
    int pre = inc - s;
    for (int w = 0; w < wv; ++w) pre += wsum[w];
    excl[2 * t] = pre;
    excl[2 * t + 1] = pre + a0;
    int base = b << 9;
#pragma unroll
    for (int j = 0; j < 2; ++j) {
        int i = 2 * t + j;
        int g = base + i;
        int c = (j == 0) ? a0 : a1;
        int ex = (j == 0) ? pre : pre + a0;
        if (g < N) {
            row_ptr[g] = pb + ex;
            if (g == N - 1) row_ptr[N] = pb + ex + c;
        }
        if (g < Npad) dinv[g] = rsqrtf((float)c + 1.0f);
    }
    __syncthreads();
    for (int e = pb + t; e < pe; e += 256) {
        unsigned pk = part_edges[e];
        int doff = (pk >> 17) & 511;
        int pos = pb + atomicAdd(&excl[doff], 1);
        ssrc[pos] = (int)(pk & 0x1FFFFu);
    }
}

// ---------- all three weight matrices -> fragment layout, one launch ----------
__device__ __forceinline__ void wfrag_one(const float* W, unsigned short* Wf, int idx,
                                          int NT, int realCols) {
    int j = idx & 7;
    int l = (idx >> 3) & 63;
    int t = idx >> 9;          // kk*NT + n
    int n = t % NT;
    int kk = t / NT;
    int k = kk * 32 + ((l >> 4) << 3) + j;
    int c = (n << 4) + (l & 15);
    float v = (c < realCols) ? W[k * realCols + c] : 0.0f;
    Wf[idx] = f2bf(v);
}

__global__ void k_wfrag_all(const float* __restrict__ W1, const float* __restrict__ W2,
                            const float* __restrict__ W3,
                            unsigned short* __restrict__ wf1,
                            unsigned short* __restrict__ wf2,
                            unsigned short* __restrict__ wf3, int Cout) {
    int idx = blockIdx.x * blockDim.x + threadIdx.x;
    if (idx < 16384) wfrag_one(W1, wf1, idx, 8, 128);
    else if (idx < 32768) wfrag_one(W2, wf2, idx - 16384, 8, 128);
    else if (idx < 40960) wfrag_one(W3, wf3, idx - 32768, 4, Cout);
}

// ---------- layer-1 GEMM with fused f32->bf16 A conversion ----------
// H'[Npad][128] = dinv[row] * (bf16(X[N][128]) @ W1)
__global__ __launch_bounds__(256) void k_gemm_f32(const float* __restrict__ X,
                                                  const unsigned short* __restrict__ Wf,
                                                  const float* __restrict__ dinv,
                                                  unsigned short* __restrict__ Hout, int N) {
    int lane = threadIdx.x & 63;
    int wv = threadIdx.x >> 6;
    size_t row0 = (size_t)(blockIdx.x * 4 + wv) * 16;
    int arowi = (int)row0 + (lane & 15);
    const float* arow = X + (size_t)arowi * 128 + ((lane >> 4) << 3);
    bool vr = arowi < N;
    f32x4 acc[8];
#pragma unroll
    for (int n = 0; n < 8; ++n) acc[n] = (f32x4){0.f, 0.f, 0.f, 0.f};
#pragma unroll
    for (int kk = 0; kk < 4; ++kk) {
        union { bf16x8 v; unsigned short u[8]; } A;
        if (vr) {
            float4 f0 = *(const float4*)(arow + kk * 32);
            float4 f1 = *(const float4*)(arow + kk * 32 + 4);
            A.u[0] = f2bf(f0.x); A.u[1] = f2bf(f0.y);
            A.u[2] = f2bf(f0.z); A.u[3] = f2bf(f0.w);
            A.u[4] = f2bf(f1.x); A.u[5] = f2bf(f1.y);
            A.u[6] = f2bf(f1.z); A.u[7] = f2bf(f1.w);
        } else {
#pragma unroll
            for (int j = 0; j < 8; ++j) A.u[j] = 0;
        }
#pragma unroll
        for (int n = 0; n < 8; ++n) {
            bf16x8 b = *(const bf16x8*)(Wf + (((kk * 8 + n) * 64 + lane) << 3));
            acc[n] = __builtin_amdgcn_mfma_f32_16x16x32_bf16(A.v, b, acc[n], 0, 0, 0);
        }
    }
    size_t crow = row0 + ((lane >> 4) << 2);
    int ccol = lane & 15;
    float dv[4];
#pragma unroll
    for (int q = 0; q < 4; ++q) dv[q] = dinv[crow + q];
#pragma unroll
    for (int n = 0; n < 8; ++n) {
#pragma unroll
        for (int q = 0; q < 4; ++q) {
            Hout[(crow + q) * 128 + n * 16 + ccol] = f2bf(acc[n][q] * dv[q]);
        }
    }
}

// ---------- GEMM (bf16 A): H'[Npad][NT*16] = dinv[row] * (A[Npad][128] @ W) ----------
template<int NT>
__global__ __launch_bounds__(256) void k_gemm(const unsigned short* __restrict__ A,
                                              const unsigned short* __restrict__ Wf,
                                              const float* __restrict__ dinv,
                                              unsigned short* __restrict__ Hout) {
    int lane = threadIdx.x & 63;
    int wv = threadIdx.x >> 6;
    int rb = blockIdx.x * 4 + wv;
    size_t row0 = (size_t)rb * 16;
    const unsigned short* arow = A + (row0 + (lane & 15)) * 128 + ((lane >> 4) << 3);
    f32x4 acc[NT];
#pragma unroll
    for (int n = 0; n < NT; ++n) acc[n] = (f32x4){0.f, 0.f, 0.f, 0.f};
#pragma unroll
    for (int kk = 0; kk < 4; ++kk) {
        bf16x8 a = *(const bf16x8*)(arow + kk * 32);
#pragma unroll
        for (int n = 0; n < NT; ++n) {
            bf16x8 b = *(const bf16x8*)(Wf + (((kk * NT + n) * 64 + lane) << 3));
            acc[n] = __builtin_amdgcn_mfma_f32_16x16x32_bf16(a, b, acc[n], 0, 0, 0);
        }
    }
    const int NCOL = NT * 16;
    size_t crow = row0 + ((lane >> 4) << 2);
    int ccol = lane & 15;
    float dv[4];
#pragma unroll
    for (int q = 0; q < 4; ++q) dv[q] = dinv[crow + q];
#pragma unroll
    for (int n = 0; n < NT; ++n) {
#pragma unroll
        for (int q = 0; q < 4; ++q) {
            Hout[(crow + q) * NCOL + n * 16 + ccol] = f2bf(acc[n][q] * dv[q]);
        }
    }
}

// ---------- aggregation (128 ch): one wave per dst node ----------
// 4 groups x 16 lanes; group g gathers edge (j+g) with dwordx4 (8 ch/lane);
// dot2-based accumulate; cross-group shfl_xor reduce at the end.
__global__ __launch_bounds__(256) void k_agg(const unsigned short* __restrict__ H,
                                             const int* __restrict__ row_ptr,
                                             const int* __restrict__ ssrc,
                                             const float* __restrict__ dinv,
                                             const float* __restrict__ bias,
                                             unsigned short* __restrict__ Out, int N) {
    int lane = threadIdx.x & 63;
    int i = blockIdx.x * 4 + (threadIdx.x >> 6);
    if (i >= N) return;
    unsigned sel_lo = SEL_LO, sel_hi = SEL_HI;
    int g = lane >> 4;
    int c16 = lane & 15;                    // 16B chunk within the 256B row
    const uint4* Hv = (const uint4*)H;      // row i = 16 uint4
    float acc[8];
#pragma unroll
    for (int c = 0; c < 8; ++c) acc[c] = 0.f;
    int e0 = row_ptr[i], e1 = row_ptr[i + 1];
    for (int base = e0; base < e1; base += 64) {
        int cnt = min(64, e1 - base);
        int sidx = (lane < cnt) ? ssrc[base + lane] : 0;
        int full = cnt & ~3;
#pragma unroll 4
        for (int j = 0; j < full; j += 4) {
            int s = __shfl(sidx, j + g, 64);
            uint4 v = Hv[((size_t)s << 4) + c16];
            DOT8(v);
        }
        int jj = full + g;
        if (jj < cnt) {
            int s = __shfl(sidx, jj, 64);
            uint4 v = Hv[((size_t)s << 4) + c16];
            DOT8(v);
        }
    }
    if (g == 0) {   // self row, added exactly once
        uint4 v = Hv[((size_t)i << 4) + c16];
        DOT8(v);
    }
#pragma unroll
    for (int c = 0; c < 8; ++c) {
        acc[c] += __shfl_xor(acc[c], 16, 64);
        acc[c] += __shfl_xor(acc[c], 32, 64);
    }
    if (g == 0) {
        float dv = dinv[i];
        const float4* bv = (const float4*)bias;
        float4 b0 = bv[c16 * 2], b1 = bv[c16 * 2 + 1];
        float r0 = fmaxf(acc[0] * dv + b0.x, 0.f);
        float r1 = fmaxf(acc[1] * dv + b0.y, 0.f);
        float r2 = fmaxf(acc[2] * dv + b0.z, 0.f);
        float r3 = fmaxf(acc[3] * dv + b0.w, 0.f);
        float r4 = fmaxf(acc[4] * dv + b1.x, 0.f);
        float r5 = fmaxf(acc[5] * dv + b1.y, 0.f);
        float r6 = fmaxf(acc[6] * dv + b1.z, 0.f);
        float r7 = fmaxf(acc[7] * dv + b1.w, 0.f);
        uint4 o;
        o.x = (unsigned)f2bf(r0) | ((unsigned)f2bf(r1) << 16);
        o.y = (unsigned)f2bf(r2) | ((unsigned)f2bf(r3) << 16);
        o.z = (unsigned)f2bf(r4) | ((unsigned)f2bf(r5) << 16);
        o.w = (unsigned)f2bf(r6) | ((unsigned)f2bf(r7) << 16);
        ((uint4*)Out)[((size_t)i << 4) + c16] = o;
    }
}

// ---------- final aggregation (64ch padded, Cout real) + bias + log_softmax ----------
// 4 groups x 16 lanes, dwordx2 (4 ch/lane); after reduce, redistribute so lane L
// owns channel L (4 shfl + 3 selects), then scalar 64-lane softmax (1 exp/lane).
__global__ __launch_bounds__(256) void k_agg3(const unsigned short* __restrict__ H,
                                              const int* __restrict__ row_ptr,
                                              const int* __restrict__ ssrc,
                                              const float* __restrict__ dinv,
                                              const float* __restrict__ b3,
                                              float* __restrict__ Out, int N, int Cout) {
    int lane = threadIdx.x & 63;
    int i = blockIdx.x * 4 + (threadIdx.x >> 6);
    if (i >= N) return;
    unsigned sel_lo = SEL_LO, sel_hi = SEL_HI;
    int g = lane >> 4;
    int c16 = lane & 15;                    // 8B chunk within the 128B row
    const uint2* Hv = (const uint2*)H;      // row i = 16 uint2
    float acc[4];
#pragma unroll
    for (int c = 0; c < 4; ++c) acc[c] = 0.f;
    int e0 = row_ptr[i], e1 = row_ptr[i + 1];
    for (int base = e0; base < e1; base += 64) {
        int cnt = min(64, e1 - base);
        int sidx = (lane < cnt) ? ssrc[base + lane] : 0;
        int full = cnt & ~3;
#pragma unroll 4
        for (int j = 0; j < full; j += 4) {
            int s = __shfl(sidx, j + g, 64);
            uint2 v = Hv[((size_t)s << 4) + c16];
            DOT4(v);
        }
        int jj = full + g;
        if (jj < cnt) {
            int s = __shfl(sidx, jj, 64);
            uint2 v = Hv[((size_t)s << 4) + c16];
            DOT4(v);
        }
    }
    if (g == 0) {
        uint2 v = Hv[((size_t)i << 4) + c16];
        DOT4(v);
    }
#pragma unroll
    for (int c = 0; c < 4; ++c) {
        acc[c] += __shfl_xor(acc[c], 16, 64);
        acc[c] += __shfl_xor(acc[c], 32, 64);
    }
    // redistribute: lane L <- element (L&3) of lane (L>>2)'s acc
    float t0 = __shfl(acc[0], lane >> 2, 64);
    float t1 = __shfl(acc[1], lane >> 2, 64);
    float t2 = __shfl(acc[2], lane >> 2, 64);
    float t3 = __shfl(acc[3], lane >> 2, 64);
    float a01 = (lane & 1) ? t1 : t0;
    float a23 = (lane & 1) ? t3 : t2;
    float av  = (lane & 2) ? a23 : a01;
    float dv = dinv[i];
    float z = (lane < Cout) ? av * dv + b3[lane] : -1e30f;
    float m = z;
    for (int off = 32; off; off >>= 1) m = fmaxf(m, __shfl_xor(m, off, 64));
    float pexp = (lane < Cout) ? expf(z - m) : 0.f;
    float ssum = pexp;
    for (int off = 32; off; off >>= 1) ssum += __shfl_xor(ssum, off, 64);
    if (lane < Cout) Out[(size_t)i * Cout + lane] = z - m - logf(ssum);
}

extern "C" void kernel_launch(void* const* d_in, const int* in_sizes, int n_in,
                              void* d_out, int out_size, void* d_ws, size_t ws_size,
                              hipStream_t stream) {
    const float* x  = (const float*)d_in[0];
    const int*   ei = (const int*)d_in[1];
    const float* W1 = (const float*)d_in[2];
    const float* b1 = (const float*)d_in[3];
    const float* W2 = (const float*)d_in[4];
    const float* b2 = (const float*)d_in[5];
    const float* W3 = (const float*)d_in[6];
    const float* b3 = (const float*)d_in[7];

    const int N = in_sizes[0] / 128;
    const int E = in_sizes[1] / 2;
    const int Cout = in_sizes[7];       // 47
    const int Npad = (N + 63) & ~63;
    const int* srcp = ei;
    const int* dstp = ei + E;

    const int NB  = (N + 511) >> 9;             // coarse buckets (196), must be <= 256
    const int nPB = (E + CHB - 1) / CHB;        // partition blocks (196)
    const int M   = NB * nPB;                   // bhist size (38416)

    // ---- workspace partition (256B aligned) ----
    char* p = (char*)d_ws;
    auto alloc = [&](size_t bytes) -> void* {
        void* r = (void*)p;
        p += (bytes + 255) & ~(size_t)255;
        return r;
    };
    float* dinv     = (float*)alloc((size_t)Npad * 4);
    int*   row_ptr  = (int*)alloc((size_t)(N + 1) * 4);
    int*   bhist    = (int*)alloc((size_t)M * 4);
    int*   bscan    = (int*)alloc((size_t)(M + 1) * 4);
    int*   part     = (int*)alloc(1024 * 4);
    unsigned* pedge = (unsigned*)alloc((size_t)E * 4);
    int*   ssrc     = (int*)alloc((size_t)E * 4);
    unsigned short* hb  = (unsigned short*)alloc((size_t)Npad * 128 * 2);
    unsigned short* ab  = (unsigned short*)alloc((size_t)Npad * 128 * 2);
    unsigned short* wf1 = (unsigned short*)alloc(128 * 128 * 2);
    unsigned short* wf2 = (unsigned short*)alloc(128 * 128 * 2);
    unsigned short* wf3 = (unsigned short*)alloc(128 * 64 * 2);

    // ---- CSR build: hist -> scan -> partition -> per-bucket counting sort ----
    const int nb2 = (M + 1023) / 1024;          // 38 blocks (<= 256)
    k_hist<<<nPB, 256, 0, stream>>>(dstp, E, nPB, bhist, NB);
    k_scan_part<<<nb2, 256, 0, stream>>>(bhist, part, M);
    k_scan_mid<<<1, 256, 0, stream>>>(part, nb2);
    k_scan_final<<<nb2, 256, 0, stream>>>(bhist, part, bscan, M);
    k_partition<<<nPB, 256, 0, stream>>>(srcp, dstp, E, nPB, bscan, pedge, NB);
    k_bucket<<<NB, 256, 0, stream>>>(pedge, bscan, nPB, N, Npad, row_ptr, dinv, ssrc);

    // weight fragment conversion (single launch for all 3)
    k_wfrag_all<<<160, 256, 0, stream>>>(W1, W2, W3, wf1, wf2, wf3, Cout);

    const int gemmGrid = Npad / 64;
    const int aggGrid = (N + 3) / 4;

    // layer 1 GEMM (fused f32->bf16 conversion of x)
    k_gemm_f32<<<gemmGrid, 256, 0, stream>>>(x, wf1, dinv, hb, N);
    k_agg<<<aggGrid, 256, 0, stream>>>(hb, row_ptr, ssrc, dinv, b1, ab, N);
    // layer 2
    k_gemm<8><<<gemmGrid, 256, 0, stream>>>(ab, wf2, dinv, hb);
    k_agg<<<aggGrid, 256, 0, stream>>>(hb, row_ptr, ssrc, dinv, b2, ab, N);
    // layer 3 (output padded to 64 cols) + log_softmax
    k_gemm<4><<<gemmGrid, 256, 0, stream>>>(ab, wf3, dinv, hb);
    k_agg3<<<aggGrid, 256, 0, stream>>>(hb, row_ptr, ssrc, dinv, b3,
                                        (float*)d_out, N, Cout);
}

// Round 12
// 285.714 us; speedup vs baseline: 1.1371x; 1.0247x over previous
//
#include <hip/hip_runtime.h>
#include <stdint.h>

typedef __bf16 bf16x8 __attribute__((ext_vector_type(8)));
typedef float f32x4 __attribute__((ext_vector_type(4)));

#define CHB 4096  // edges per partition block

__device__ __forceinline__ unsigned short f2bf(float f) {
    union { float f; unsigned u; } x; x.f = f;
    unsigned r = x.u + 0x7fffu + ((x.u >> 16) & 1u);
    return (unsigned short)(r >> 16);
}

// acc += pk.bf16[0]*sel.bf16[0] + pk.bf16[1]*sel.bf16[1]  (one VOP3P op)
__device__ __forceinline__ void dot2acc(float& a, unsigned pk, unsigned sel) {
    asm("v_dot2_f32_bf16 %0, %1, %2, %0" : "+v"(a) : "v"(pk), "v"(sel));
}

// selector constants: bf16 pair (1.0, 0.0) and (0.0, 1.0)
#define SEL_LO 0x00003F80u
#define SEL_HI 0x3F800000u

#define DOT8(v)                                      \
    dot2acc(acc[0], (v).x, sel_lo); dot2acc(acc[1], (v).x, sel_hi); \
    dot2acc(acc[2], (v).y, sel_lo); dot2acc(acc[3], (v).y, sel_hi); \
    dot2acc(acc[4], (v).z, sel_lo); dot2acc(acc[5], (v).z, sel_hi); \
    dot2acc(acc[6], (v).w, sel_lo); dot2acc(acc[7], (v).w, sel_hi);

#define DOT4(v)                                      \
    dot2acc(acc[0], (v).x, sel_lo); dot2acc(acc[1], (v).x, sel_hi); \
    dot2acc(acc[2], (v).y, sel_lo); dot2acc(acc[3], (v).y, sel_hi);

// ---------- pass A: per-(bucket,block) histogram. bucket = dst>>8 ----------
__global__ __launch_bounds__(256) void k_hist(const int* __restrict__ dst, int E, int nPB,
                                              int* __restrict__ bhist, int NB) {
    __shared__ int h[512];
    int t = threadIdx.x;
    h[t] = 0; h[t + 256] = 0;
    __syncthreads();
    int blk = blockIdx.x;
    int hi = min((blk + 1) * CHB, E);
    for (int e = blk * CHB + t; e < hi; e += 256) atomicAdd(&h[dst[e] >> 8], 1);
    __syncthreads();
    if (t < NB) bhist[t * nPB + blk] = h[t];
    int t2 = t + 256;
    if (t2 < NB) bhist[t2 * nPB + blk] = h[t2];
}

// ---------- hierarchical scan (generic): in[M] -> out[M+1] exclusive ----------
__global__ __launch_bounds__(256) void k_scan_part(const int* __restrict__ deg,
                                                   int* __restrict__ part, int N) {
    __shared__ int wsum[4];
    int t = threadIdx.x;
    int lane = t & 63, wv = t >> 6;
    int base = blockIdx.x * 1024 + t * 4;
    int s = 0;
#pragma unroll
    for (int j = 0; j < 4; ++j) {
        int i = base + j;
        if (i < N) s += deg[i];
    }
    for (int off = 1; off < 64; off <<= 1) s += __shfl_xor(s, off, 64);
    if (lane == 0) wsum[wv] = s;
    __syncthreads();
    if (t == 0) part[blockIdx.x] = wsum[0] + wsum[1] + wsum[2] + wsum[3];
}

__global__ void k_scan_mid(int* __restrict__ part, int nb) {
    __shared__ int buf[256];
    int t = threadIdx.x;
    buf[t] = (t < nb) ? part[t] : 0;
    __syncthreads();
    for (int off = 1; off < 256; off <<= 1) {
        int v = buf[t];
        int u = (t >= off) ? buf[t - off] : 0;
        __syncthreads();
        buf[t] = v + u;
        __syncthreads();
    }
    if (t < nb) part[t] = (t == 0) ? 0 : buf[t - 1];
}

__global__ __launch_bounds__(256) void k_scan_final(const int* __restrict__ deg,
                                                    const int* __restrict__ part,
                                                    int* __restrict__ out, int N) {
    __shared__ int wsum[4];
    int t = threadIdx.x;
    int lane = t & 63, wv = t >> 6;
    int base = blockIdx.x * 1024 + t * 4;
    int v[4];
    int s = 0;
#pragma unroll
    for (int j = 0; j < 4; ++j) {
        int i = base + j;
        v[j] = (i < N) ? deg[i] : 0;
        s += v[j];
    }
    int inc = s;
    for (int off = 1; off < 64; off <<= 1) {
        int u = __shfl_up(inc, off, 64);
        if (lane >= off) inc += u;
    }
    if (lane == 63) wsum[wv] = inc;
    __syncthreads();
    int excl = part[blockIdx.x] + inc - s;
    for (int w = 0; w < wv; ++w) excl += wsum[w];
#pragma unroll
    for (int j = 0; j < 4; ++j) {
        int i = base + j;
        if (i < N) {
            out[i] = excl;
            excl += v[j];
            if (i == N - 1) out[N] = excl;
        }
    }
}

// ---------- pass B: partition edges into bucket-contiguous regions ----------
__global__ __launch_bounds__(256) void k_partition(const int* __restrict__ src,
                                                   const int* __restrict__ dst, int E,
                                                   int nPB, const int* __restrict__ bscan,
                                                   unsigned* __restrict__ part_edges, int NB) {
    __shared__ int cur[512];
    int t = threadIdx.x;
    int blk = blockIdx.x;
    if (t < NB) cur[t] = bscan[t * nPB + blk];
    int t2 = t + 256;
    if (t2 < NB) cur[t2] = bscan[t2 * nPB + blk];
    __syncthreads();
    int hi = min((blk + 1) * CHB, E);
    for (int e = blk * CHB + t; e < hi; e += 256) {
        int d = dst[e];
        int s = src[e];
        int pos = atomicAdd(&cur[d >> 8], 1);
        part_edges[pos] = ((unsigned)(d & 255) << 17) | (unsigned)s;
    }
}

// ---------- pass C: per-bucket (256 nodes) counting sort -> row_ptr, dinv, ssrc ----------
__global__ __launch_bounds__(256) void k_bucket(const unsigned* __restrict__ part_edges,
                                                const int* __restrict__ bscan, int nPB,
                                                int N, int Npad, int* __restrict__ row_ptr,
                                                float* __restrict__ dinv,
                                                int* __restrict__ ssrc) {
    __shared__ int cnt[256];
    __shared__ int excl[256];
    __shared__ int wsum[4];
    int t = threadIdx.x;
    int b = blockIdx.x;
    int pb = bscan[b * nPB];
    int pe = bscan[(b + 1) * nPB];   // bscan[M] == E for the last bucket
    cnt[t] = 0;
    __syncthreads();
    for (int e = pb + t; e < pe; e += 256)
        atomicAdd(&cnt[(part_edges[e] >> 17) & 255], 1);
    __syncthreads();
    int s = cnt[t];
    int lane = t & 63, wv = t >> 6;
    int inc = s;
    for (int off = 1; off < 64; off <<= 1) {
        int u = __shfl_up(inc, off, 64);
        if (lane >= off) inc += u;
    }
    if (lane == 63) wsum[wv] = inc;
    __syncthreads();
    int pre = inc - s;
    for (int w = 0; w < wv; ++w) pre += wsum[w];
    excl[t] = pre;
    int g = (b << 8) + t;
    if (g < N) {
        row_ptr[g] = pb + pre;
        if (g == N - 1) row_ptr[N] = pb + pre + s;
    }
    if (g < Npad) dinv[g] = rsqrtf((float)s + 1.0f);
    __syncthreads();
    for (int e = pb + t; e < pe; e += 256) {
        unsigned pk = part_edges[e];
        int doff = (pk >> 17) & 255;
        int pos = pb + atomicAdd(&excl[doff], 1);
        ssrc[pos] = (int)(pk & 0x1FFFFu);
    }
}

// ---------- all three weight matrices -> fragment layout, one launch ----------
__device__ __forceinline__ void wfrag_one(const float* W, unsigned short* Wf, int idx,
                                          int NT, int realCols) {
    int j = idx & 7;
    int l = (idx >> 3) & 63;
    int t = idx >> 9;          // kk*NT + n
    int n = t % NT;
    int kk = t / NT;
    int k = kk * 32 + ((l >> 4) << 3) + j;
    int c = (n << 4) + (l & 15);
    float v = (c < realCols) ? W[k * realCols + c] : 0.0f;
    Wf[idx] = f2bf(v);
}

__global__ void k_wfrag_all(const float* __restrict__ W1, const float* __restrict__ W2,
                            const float* __restrict__ W3,
                            unsigned short* __restrict__ wf1,
                            unsigned short* __restrict__ wf2,
                            unsigned short* __restrict__ wf3, int Cout) {
    int idx = blockIdx.x * blockDim.x + threadIdx.x;
    if (idx < 16384) wfrag_one(W1, wf1, idx, 8, 128);
    else if (idx < 32768) wfrag_one(W2, wf2, idx - 16384, 8, 128);
    else if (idx < 40960) wfrag_one(W3, wf3, idx - 32768, 4, Cout);
}

// ---------- layer-1 GEMM with fused f32->bf16 A conversion ----------
// H'[Npad][128] = dinv[row] * (bf16(X[N][128]) @ W1)
__global__ __launch_bounds__(256) void k_gemm_f32(const float* __restrict__ X,
                                                  const unsigned short* __restrict__ Wf,
                                                  const float* __restrict__ dinv,
                                                  unsigned short* __restrict__ Hout, int N) {
    int lane = threadIdx.x & 63;
    int wv = threadIdx.x >> 6;
    size_t row0 = (size_t)(blockIdx.x * 4 + wv) * 16;
    int arowi = (int)row0 + (lane & 15);
    const float* arow = X + (size_t)arowi * 128 + ((lane >> 4) << 3);
    bool vr = arowi < N;
    f32x4 acc[8];
#pragma unroll
    for (int n = 0; n < 8; ++n) acc[n] = (f32x4){0.f, 0.f, 0.f, 0.f};
#pragma unroll
    for (int kk = 0; kk < 4; ++kk) {
        union { bf16x8 v; unsigned short u[8]; } A;
        if (vr) {
            float4 f0 = *(const float4*)(arow + kk * 32);
            float4 f1 = *(const float4*)(arow + kk * 32 + 4);
            A.u[0] = f2bf(f0.x); A.u[1] = f2bf(f0.y);
            A.u[2] = f2bf(f0.z); A.u[3] = f2bf(f0.w);
            A.u[4] = f2bf(f1.x); A.u[5] = f2bf(f1.y);
            A.u[6] = f2bf(f1.z); A.u[7] = f2bf(f1.w);
        } else {
#pragma unroll
            for (int j = 0; j < 8; ++j) A.u[j] = 0;
        }
#pragma unroll
        for (int n = 0; n < 8; ++n) {
            bf16x8 b = *(const bf16x8*)(Wf + (((kk * 8 + n) * 64 + lane) << 3));
            acc[n] = __builtin_amdgcn_mfma_f32_16x16x32_bf16(A.v, b, acc[n], 0, 0, 0);
        }
    }
    size_t crow = row0 + ((lane >> 4) << 2);
    int ccol = lane & 15;
    float dv[4];
#pragma unroll
    for (int q = 0; q < 4; ++q) dv[q] = dinv[crow + q];
#pragma unroll
    for (int n = 0; n < 8; ++n) {
#pragma unroll
        for (int q = 0; q < 4; ++q) {
            Hout[(crow + q) * 128 + n * 16 + ccol] = f2bf(acc[n][q] * dv[q]);
        }
    }
}

// ---------- GEMM (bf16 A): H'[Npad][NT*16] = dinv[row] * (A[Npad][128] @ W) ----------
template<int NT>
__global__ __launch_bounds__(256) void k_gemm(const unsigned short* __restrict__ A,
                                              const unsigned short* __restrict__ Wf,
                                              const float* __restrict__ dinv,
                                              unsigned short* __restrict__ Hout) {
    int lane = threadIdx.x & 63;
    int wv = threadIdx.x >> 6;
    int rb = blockIdx.x * 4 + wv;
    size_t row0 = (size_t)rb * 16;
    const unsigned short* arow = A + (row0 + (lane & 15)) * 128 + ((lane >> 4) << 3);
    f32x4 acc[NT];
#pragma unroll
    for (int n = 0; n < NT; ++n) acc[n] = (f32x4){0.f, 0.f, 0.f, 0.f};
#pragma unroll
    for (int kk = 0; kk < 4; ++kk) {
        bf16x8 a = *(const bf16x8*)(arow + kk * 32);
#pragma unroll
        for (int n = 0; n < NT; ++n) {
            bf16x8 b = *(const bf16x8*)(Wf + (((kk * NT + n) * 64 + lane) << 3));
            acc[n] = __builtin_amdgcn_mfma_f32_16x16x32_bf16(a, b, acc[n], 0, 0, 0);
        }
    }
    const int NCOL = NT * 16;
    size_t crow = row0 + ((lane >> 4) << 2);
    int ccol = lane & 15;
    float dv[4];
#pragma unroll
    for (int q = 0; q < 4; ++q) dv[q] = dinv[crow + q];
#pragma unroll
    for (int n = 0; n < NT; ++n) {
#pragma unroll
        for (int q = 0; q < 4; ++q) {
            Hout[(crow + q) * NCOL + n * 16 + ccol] = f2bf(acc[n][q] * dv[q]);
        }
    }
}

// ---------- aggregation (128 ch): one wave per dst node ----------
// 4 groups x 16 lanes; group g gathers edge (j+g) with dwordx4 (8 ch/lane);
// dot2-based accumulate; cross-group shfl_xor reduce at the end.
__global__ __launch_bounds__(256) void k_agg(const unsigned short* __restrict__ H,
                                             const int* __restrict__ row_ptr,
                                             const int* __restrict__ ssrc,
                                             const float* __restrict__ dinv,
                                             const float* __restrict__ bias,
                                             unsigned short* __restrict__ Out, int N) {
    int lane = threadIdx.x & 63;
    int i = blockIdx.x * 4 + (threadIdx.x >> 6);
    if (i >= N) return;
    unsigned sel_lo = SEL_LO, sel_hi = SEL_HI;
    int g = lane >> 4;
    int c16 = lane & 15;                    // 16B chunk within the 256B row
    const uint4* Hv = (const uint4*)H;      // row i = 16 uint4
    float acc[8];
#pragma unroll
    for (int c = 0; c < 8; ++c) acc[c] = 0.f;
    int e0 = row_ptr[i], e1 = row_ptr[i + 1];
    for (int base = e0; base < e1; base += 64) {
        int cnt = min(64, e1 - base);
        int sidx = (lane < cnt) ? ssrc[base + lane] : 0;
        int full = cnt & ~3;
#pragma unroll 4
        for (int j = 0; j < full; j += 4) {
            int s = __shfl(sidx, j + g, 64);
            uint4 v = Hv[((size_t)s << 4) + c16];
            DOT8(v);
        }
        int jj = full + g;
        if (jj < cnt) {
            int s = __shfl(sidx, jj, 64);
            uint4 v = Hv[((size_t)s << 4) + c16];
            DOT8(v);
        }
    }
    if (g == 0) {   // self row, added exactly once
        uint4 v = Hv[((size_t)i << 4) + c16];
        DOT8(v);
    }
#pragma unroll
    for (int c = 0; c < 8; ++c) {
        acc[c] += __shfl_xor(acc[c], 16, 64);
        acc[c] += __shfl_xor(acc[c], 32, 64);
    }
    if (g == 0) {
        float dv = dinv[i];
        const float4* bv = (const float4*)bias;
        float4 b0 = bv[c16 * 2], b1 = bv[c16 * 2 + 1];
        float r0 = fmaxf(acc[0] * dv + b0.x, 0.f);
        float r1 = fmaxf(acc[1] * dv + b0.y, 0.f);
        float r2 = fmaxf(acc[2] * dv + b0.z, 0.f);
        float r3 = fmaxf(acc[3] * dv + b0.w, 0.f);
        float r4 = fmaxf(acc[4] * dv + b1.x, 0.f);
        float r5 = fmaxf(acc[5] * dv + b1.y, 0.f);
        float r6 = fmaxf(acc[6] * dv + b1.z, 0.f);
        float r7 = fmaxf(acc[7] * dv + b1.w, 0.f);
        uint4 o;
        o.x = (unsigned)f2bf(r0) | ((unsigned)f2bf(r1) << 16);
        o.y = (unsigned)f2bf(r2) | ((unsigned)f2bf(r3) << 16);
        o.z = (unsigned)f2bf(r4) | ((unsigned)f2bf(r5) << 16);
        o.w = (unsigned)f2bf(r6) | ((unsigned)f2bf(r7) << 16);
        ((uint4*)Out)[((size_t)i << 4) + c16] = o;
    }
}

// ---------- final aggregation (64ch padded, Cout real) + bias + log_softmax ----------
// 4 groups x 16 lanes, dwordx2 (4 ch/lane); after reduce, redistribute so lane L
// owns channel L (4 shfl + 3 selects), then scalar 64-lane softmax (1 exp/lane).
__global__ __launch_bounds__(256) void k_agg3(const unsigned short* __restrict__ H,
                                              const int* __restrict__ row_ptr,
                                              const int* __restrict__ ssrc,
                                              const float* __restrict__ dinv,
                                              const float* __restrict__ b3,
                                              float* __restrict__ Out, int N, int Cout) {
    int lane = threadIdx.x & 63;
    int i = blockIdx.x * 4 + (threadIdx.x >> 6);
    if (i >= N) return;
    unsigned sel_lo = SEL_LO, sel_hi = SEL_HI;
    int g = lane >> 4;
    int c16 = lane & 15;                    // 8B chunk within the 128B row
    const uint2* Hv = (const uint2*)H;      // row i = 16 uint2
    float acc[4];
#pragma unroll
    for (int c = 0; c < 4; ++c) acc[c] = 0.f;
    int e0 = row_ptr[i], e1 = row_ptr[i + 1];
    for (int base = e0; base < e1; base += 64) {
        int cnt = min(64, e1 - base);
        int sidx = (lane < cnt) ? ssrc[base + lane] : 0;
        int full = cnt & ~3;
#pragma unroll 4
        for (int j = 0; j < full; j += 4) {
            int s = __shfl(sidx, j + g, 64);
            uint2 v = Hv[((size_t)s << 4) + c16];
            DOT4(v);
        }
        int jj = full + g;
        if (jj < cnt) {
            int s = __shfl(sidx, jj, 64);
            uint2 v = Hv[((size_t)s << 4) + c16];
            DOT4(v);
        }
    }
    if (g == 0) {
        uint2 v = Hv[((size_t)i << 4) + c16];
        DOT4(v);
    }
#pragma unroll
    for (int c = 0; c < 4; ++c) {
        acc[c] += __shfl_xor(acc[c], 16, 64);
        acc[c] += __shfl_xor(acc[c], 32, 64);
    }
    // redistribute: lane L <- element (L&3) of lane (L>>2)'s acc
    float t0 = __shfl(acc[0], lane >> 2, 64);
    float t1 = __shfl(acc[1], lane >> 2, 64);
    float t2 = __shfl(acc[2], lane >> 2, 64);
    float t3 = __shfl(acc[3], lane >> 2, 64);
    float a01 = (lane & 1) ? t1 : t0;
    float a23 = (lane & 1) ? t3 : t2;
    float av  = (lane & 2) ? a23 : a01;
    float dv = dinv[i];
    float z = (lane < Cout) ? av * dv + b3[lane] : -1e30f;
    float m = z;
    for (int off = 32; off; off >>= 1) m = fmaxf(m, __shfl_xor(m, off, 64));
    float pexp = (lane < Cout) ? expf(z - m) : 0.f;
    float ssum = pexp;
    for (int off = 32; off; off >>= 1) ssum += __shfl_xor(ssum, off, 64);
    if (lane < Cout) Out[(size_t)i * Cout + lane] = z - m - logf(ssum);
}

extern "C" void kernel_launch(void* const* d_in, const int* in_sizes, int n_in,
                              void* d_out, int out_size, void* d_ws, size_t ws_size,
                              hipStream_t stream) {
    const float* x  = (const float*)d_in[0];
    const int*   ei = (const int*)d_in[1];
    const float* W1 = (const float*)d_in[2];
    const float* b1 = (const float*)d_in[3];
    const float* W2 = (const float*)d_in[4];
    const float* b2 = (const float*)d_in[5];
    const float* W3 = (const float*)d_in[6];
    const float* b3 = (const float*)d_in[7];

    const int N = in_sizes[0] / 128;
    const int E = in_sizes[1] / 2;
    const int Cout = in_sizes[7];       // 47
    const int Npad = (N + 63) & ~63;
    const int* srcp = ei;
    const int* dstp = ei + E;

    const int NB  = (N + 255) >> 8;             // coarse buckets (391), must be <= 512
    const int nPB = (E + CHB - 1) / CHB;        // partition blocks (391)
    const int M   = NB * nPB;                   // bhist size (~153k, scan max 262144)

    // ---- workspace partition (256B aligned) ----
    char* p = (char*)d_ws;
    auto alloc = [&](size_t bytes) -> void* {
        void* r = (void*)p;
        p += (bytes + 255) & ~(size_t)255;
        return r;
    };
    float* dinv     = (float*)alloc((size_t)Npad * 4);
    int*   row_ptr  = (int*)alloc((size_t)(N + 1) * 4);
    int*   bhist    = (int*)alloc((size_t)M * 4);
    int*   bscan    = (int*)alloc((size_t)(M + 1) * 4);
    int*   part     = (int*)alloc(1024 * 4);
    unsigned* pedge = (unsigned*)alloc((size_t)E * 4);
    int*   ssrc     = (int*)alloc((size_t)E * 4);
    unsigned short* hb  = (unsigned short*)alloc((size_t)Npad * 128 * 2);
    unsigned short* ab  = (unsigned short*)alloc((size_t)Npad * 128 * 2);
    unsigned short* wf1 = (unsigned short*)alloc(128 * 128 * 2);
    unsigned short* wf2 = (unsigned short*)alloc(128 * 128 * 2);
    unsigned short* wf3 = (unsigned short*)alloc(128 * 64 * 2);

    // ---- CSR build: hist -> scan -> partition -> per-bucket counting sort ----
    const int nb2 = (M + 1023) / 1024;          // ~150 blocks (<= 256)
    k_hist<<<nPB, 256, 0, stream>>>(dstp, E, nPB, bhist, NB);
    k_scan_part<<<nb2, 256, 0, stream>>>(bhist, part, M);
    k_scan_mid<<<1, 256, 0, stream>>>(part, nb2);
    k_scan_final<<<nb2, 256, 0, stream>>>(bhist, part, bscan, M);
    k_partition<<<nPB, 256, 0, stream>>>(srcp, dstp, E, nPB, bscan, pedge, NB);
    k_bucket<<<NB, 256, 0, stream>>>(pedge, bscan, nPB, N, Npad, row_ptr, dinv, ssrc);

    // weight fragment conversion (single launch for all 3)
    k_wfrag_all<<<160, 256, 0, stream>>>(W1, W2, W3, wf1, wf2, wf3, Cout);

    const int gemmGrid = Npad / 64;
    const int aggGrid = (N + 3) / 4;

    // layer 1 GEMM (fused f32->bf16 conversion of x)
    k_gemm_f32<<<gemmGrid, 256, 0, stream>>>(x, wf1, dinv, hb, N);
    k_agg<<<aggGrid, 256, 0, stream>>>(hb, row_ptr, ssrc, dinv, b1, ab, N);
    // layer 2
    k_gemm<8><<<gemmGrid, 256, 0, stream>>>(ab, wf2, dinv, hb);
    k_agg<<<aggGrid, 256, 0, stream>>>(hb, row_ptr, ssrc, dinv, b2, ab, N);
    // layer 3 (output padded to 64 cols) + log_softmax
    k_gemm<4><<<gemmGrid, 256, 0, stream>>>(ab, wf3, dinv, hb);
    k_agg3<<<aggGrid, 256, 0, stream>>>(hb, row_ptr, ssrc, dinv, b3,
                                        (float*)d_out, N, Cout);
}